// Round 6
// baseline (520.223 us; speedup 1.0000x reference)
//
#include <hip/hip_runtime.h>
#include <math.h>

#define B    512
#define L    1024
#define K    8
#define NR   512
#define S    20
#define EXT  26
#define SS   (S*S)            // 400
#define PD   24               // padded matrix dim (zero pad is matmul-self-consistent)
#define PDSQ (PD*PD)          // 576
#define ROWF (K*EXT)          // 208 floats per (b,l)
#define BROW (L*ROWF)         // 212992 floats per b

__device__ __forceinline__ float softplusf(float x) {
    return fmaxf(x, 0.0f) + log1pf(expf(-fabsf(x)));
}

// wave-local ordering fence: per-wave DS ops complete in order on CDNA, so
// for a wave working on its OWN LDS patch this replaces __syncthreads.
__device__ __forceinline__ void wave_fence() {
    __builtin_amdgcn_wave_barrier();
}

// one-hot helper: 1.0f if (e % 26) == inp, else 0 (e < 212)
__device__ __forceinline__ float onehotv(int e, int inp) {
    int k  = (e * 1261) >> 15;      // floor(e/26) for e < 212
    int me = e - 26 * k;
    return (me == inp) ? 1.f : 0.f;
}

// ---------------------------------------------------------------------------
// ONE fused kernel. Block = one b (512 blocks, 512 threads = 8 waves).
//   Phase A (FIRST, fire-and-forget): rows with inp>=20 are pure one-hot,
//            independent of P -> store them immediately (23% of output,
//            ~100 MB) so they drain on the HBM pipe while expm runs on the
//            VALU/LDS pipes. Values ALU-generated; full-row (13-line) writes.
//   Phase 1: per-wave expm (8x8 lanes, 3x3 reg tile, A cols in regs),
//            order-10 Taylor + 6 squarings; squarings use a P/P^T pair of
//            LDS buffers so BOTH operands stream as ds_read_b128 rows.
//   Phase B: after the single __syncthreads, store rows with inp<20 from
//            the 20x208 Row LUT (division-free period-13 sweep).
// ---------------------------------------------------------------------------
__global__ __launch_bounds__(512, 2) void fused_kernel(
    const int*   __restrict__ inputs,        // B,L
    const int*   __restrict__ rate_indices,  // B
    const float* __restrict__ tau_kernel,    // NR
    const float* __restrict__ exch,          // K,S,S
    const float* __restrict__ freq,          // S
    float* __restrict__ out)                 // B,L,208
{
    __shared__ __align__(16) float M[K][2][PDSQ];   // 36864 B
    __shared__ __align__(16) float Row[S*ROWF];     // 16640 B (rows < 20 only)
    __shared__ int   inp_sh[L];                     // 4096 B
    __shared__ float diag_sh[K][S];
    __shared__ float mue_sh[K];

    const int b    = blockIdx.x;
    const int t    = threadIdx.x;
    const int w    = t >> 6;          // wave id == matrix k
    const int lane = t & 63;
    const int li = lane >> 3, lj = lane & 7;
    const int r0 = 3*li, c0 = 3*lj;   // 3x3 tile origin in 24x24

    const int* gin = inputs + b * L;
    float4* out4 = (float4*)out + (size_t)b * (BROW/4);

    // division-free sweep tables: u = t + 512*j + 6656*i (j<13, i<8)
    int l0[13], qq[13];
    {
        int uu = t;
        #pragma unroll
        for (int j = 0; j < 13; ++j) {
            l0[j] = uu / 52;
            qq[j] = uu - l0[j] * 52;
            uu += 512;
        }
    }

    // ---- inp -> LDS (consumed by phase B after the barrier) ----
    for (int u = t; u < L; u += 512) inp_sh[u] = gin[u];

    // ---- Phase A: one-hot rows (inp >= 20), P-independent, store NOW ----
    #pragma unroll 1
    for (int i = 0; i < 8; ++i) {
        int lbase = i << 7;
        int ubase = t + i * 6656;
        #pragma unroll
        for (int j = 0; j < 13; ++j) {
            int inp = gin[l0[j] + lbase];
            if (inp >= S) {
                int e = qq[j] << 2;
                float4 v;
                v.x = onehotv(e,     inp);
                v.y = onehotv(e + 1, inp);
                v.z = onehotv(e + 2, inp);
                v.w = onehotv(e + 3, inp);
                out4[ubase + (j << 9)] = v;
            }
        }
    }

    // ---- Row LUT zero-pad cols (rows<20, s>=20): disjoint from tile cells ----
    for (int idx = t; idx < S * 48; idx += 512) {
        int r   = idx / 48;
        int c48 = idx - r * 48;
        int k   = c48 / 6;
        int s   = 20 + (c48 - k * 6);
        Row[r*ROWF + k*EXT + s] = 0.f;
    }

    // ---- Phase 1: build A = (Q_w / mue) * tau / 2^6 in M0 ----
    float* M0 = &M[w][0][0];
    float* M1 = &M[w][1][0];
    for (int e = lane; e < 2*PDSQ; e += 64) M0[e] = 0.f;
    float tau = softplusf(tau_kernel[rate_indices[b]]);   // uniform, per-lane
    wave_fence();

    const float* E = exch + w * SS;
    for (int e = lane; e < SS; e += 64) {
        int r = e / S, c = e - r*S;
        float v = 0.f;
        if (r != c)
            v = softplusf(0.5f * (E[r*S + c] + E[c*S + r])) * freq[c];
        M0[r*PD + c] = v;
    }
    wave_fence();
    if (lane < S) {
        float d = 0.f;
        #pragma unroll
        for (int j = 0; j < S; ++j) d += M0[lane*PD + j];
        diag_sh[w][lane] = d;
    }
    wave_fence();
    if (lane == 0) {
        float m = 0.f;
        #pragma unroll
        for (int s = 0; s < S; ++s) m += freq[s] * diag_sh[w][s];
        mue_sh[w] = fmaxf(m, 1e-16f);
    }
    wave_fence();
    {
        float scale = tau * 0.015625f;
        float mue   = mue_sh[w];
        for (int e = lane; e < SS; e += 64) {
            int r = e / S, c = e - r*S;
            float v = (r == c) ? -diag_sh[w][r] : M0[r*PD + c];
            M0[r*PD + c] = (v / mue) * scale;
        }
    }
    wave_fence();

    // ---- expm: A cols in regs, P=I+A, order-10 Taylor, 6 squarings ----
    float Ac[S][3];
    #pragma unroll
    for (int j = 0; j < S; ++j) {
        #pragma unroll
        for (int d = 0; d < 3; ++d)
            Ac[j][d] = M0[j*PD + c0 + d];
    }

    float P[3][3];
    #pragma unroll
    for (int dr = 0; dr < 3; ++dr)
        #pragma unroll
        for (int dc = 0; dc < 3; ++dc) {
            int r = r0 + dr, c = c0 + dc;
            P[dr][dc] = M0[r*PD + c] + ((r == c && r < S) ? 1.f : 0.f);
        }

    const float* Tc = M0;
    float* Tn = M1;
    #pragma unroll 1
    for (int i = 2; i <= 10; ++i) {
        float C[3][3] = {{0.f,0.f,0.f},{0.f,0.f,0.f},{0.f,0.f,0.f}};
        #pragma unroll
        for (int jc = 0; jc < 5; ++jc) {
            float4 a0 = *(const float4*)&Tc[(r0+0)*PD + 4*jc];
            float4 a1 = *(const float4*)&Tc[(r0+1)*PD + 4*jc];
            float4 a2 = *(const float4*)&Tc[(r0+2)*PD + 4*jc];
            float t0[4] = {a0.x, a0.y, a0.z, a0.w};
            float t1[4] = {a1.x, a1.y, a1.z, a1.w};
            float t2[4] = {a2.x, a2.y, a2.z, a2.w};
            #pragma unroll
            for (int dj = 0; dj < 4; ++dj) {
                int j = 4*jc + dj;
                #pragma unroll
                for (int dc = 0; dc < 3; ++dc) {
                    C[0][dc] = fmaf(t0[dj], Ac[j][dc], C[0][dc]);
                    C[1][dc] = fmaf(t1[dj], Ac[j][dc], C[1][dc]);
                    C[2][dc] = fmaf(t2[dj], Ac[j][dc], C[2][dc]);
                }
            }
        }
        float inv = 1.0f / (float)i;
        #pragma unroll
        for (int dr = 0; dr < 3; ++dr)
            #pragma unroll
            for (int dc = 0; dc < 3; ++dc) {
                C[dr][dc] *= inv;
                P[dr][dc] += C[dr][dc];
                Tn[(r0+dr)*PD + c0 + dc] = C[dr][dc];
            }
        wave_fence();
        float* tmp = (float*)Tc; Tc = Tn; Tn = tmp;
    }

    // squarings with P (X=M0) and P^T (Y=M1): both operands as b128 rows
    float* X = M0;
    float* Y = M1;
    #pragma unroll 1
    for (int sq = 0; sq < 6; ++sq) {
        #pragma unroll
        for (int dr = 0; dr < 3; ++dr)
            #pragma unroll
            for (int dc = 0; dc < 3; ++dc) {
                X[(r0+dr)*PD + c0+dc] = P[dr][dc];
                Y[(c0+dc)*PD + r0+dr] = P[dr][dc];
            }
        wave_fence();
        float C[3][3] = {{0.f,0.f,0.f},{0.f,0.f,0.f},{0.f,0.f,0.f}};
        #pragma unroll
        for (int jc = 0; jc < 5; ++jc) {
            float4 a0 = *(const float4*)&X[(r0+0)*PD + 4*jc];
            float4 a1 = *(const float4*)&X[(r0+1)*PD + 4*jc];
            float4 a2 = *(const float4*)&X[(r0+2)*PD + 4*jc];
            float4 b0 = *(const float4*)&Y[(c0+0)*PD + 4*jc];
            float4 b1 = *(const float4*)&Y[(c0+1)*PD + 4*jc];
            float4 b2 = *(const float4*)&Y[(c0+2)*PD + 4*jc];
            float ta[3][4] = {{a0.x,a0.y,a0.z,a0.w},
                              {a1.x,a1.y,a1.z,a1.w},
                              {a2.x,a2.y,a2.z,a2.w}};
            float tb[3][4] = {{b0.x,b0.y,b0.z,b0.w},
                              {b1.x,b1.y,b1.z,b1.w},
                              {b2.x,b2.y,b2.z,b2.w}};
            #pragma unroll
            for (int dj = 0; dj < 4; ++dj)
                #pragma unroll
                for (int dr = 0; dr < 3; ++dr)
                    #pragma unroll
                    for (int dc = 0; dc < 3; ++dc)
                        C[dr][dc] = fmaf(ta[dr][dj], tb[dc][dj], C[dr][dc]);
        }
        #pragma unroll
        for (int dr = 0; dr < 3; ++dr)
            #pragma unroll
            for (int dc = 0; dc < 3; ++dc)
                P[dr][dc] = C[dr][dc];
        wave_fence();   // per-wave LDS in-order: next writes can't pass reads
    }

    // ---- P tiles -> Row LUT (r<20, c<20 cells; disjoint from pad init) ----
    #pragma unroll
    for (int dr = 0; dr < 3; ++dr) {
        int r = r0 + dr; if (r >= S) continue;
        #pragma unroll
        for (int dc = 0; dc < 3; ++dc) {
            int c = c0 + dc; if (c >= S) continue;
            Row[r*ROWF + w*EXT + c] = P[dr][dc];
        }
    }
    __syncthreads();   // the ONLY block-wide barrier

    // ---- Phase B: rows with inp<20 from LUT ----
    const float4* Row4 = (const float4*)Row;
    #pragma unroll 1
    for (int i = 0; i < 8; ++i) {
        int lbase = i << 7;
        int ubase = t + i * 6656;
        #pragma unroll
        for (int j = 0; j < 13; ++j) {
            int inp = inp_sh[l0[j] + lbase];
            if (inp < S)
                out4[ubase + (j << 9)] = Row4[inp * 52 + qq[j]];
        }
    }
}

// ---------------------------------------------------------------------------
extern "C" void kernel_launch(void* const* d_in, const int* in_sizes, int n_in,
                              void* d_out, int out_size, void* d_ws, size_t ws_size,
                              hipStream_t stream) {
    const int*   inputs  = (const int*)  d_in[0];  // (B,L) int32
    const int*   rate_ix = (const int*)  d_in[1];  // (B,) int32
    const float* tau_k   = (const float*)d_in[2];  // (NR,) f32
    const float* exch    = (const float*)d_in[3];  // (K,S,S) f32
    const float* freq    = (const float*)d_in[4];  // (S,) f32
    float* out = (float*)d_out;

    (void)d_ws; (void)ws_size;

    fused_kernel<<<B, 512, 0, stream>>>(inputs, rate_ix, tau_k, exch, freq, out);
}

// Round 7
// 487.276 us; speedup vs baseline: 1.0676x; 1.0676x over previous
//
#include <hip/hip_runtime.h>
#include <math.h>

#define B    512
#define L    1024
#define K    8
#define NR   512
#define S    20
#define EXT  26
#define SS   (S*S)            // 400
#define PD   24               // padded matrix dim (zero pad is matmul-self-consistent)
#define PDSQ (PD*PD)          // 576
#define ROWF (K*EXT)          // 208 floats per (b,l)
#define BROW (L*ROWF)         // 212992 floats per b
#define LUTF (EXT*ROWF)       // 5408 floats = 1352 float4
#define LUT4 (LUTF/4)         // 1352
#define B4   (BROW/4)         // 53248 float4 per b
#define H4   (B4/2)           // 26624 float4 per half

__device__ __forceinline__ float softplusf(float x) {
    return fmaxf(x, 0.0f) + log1pf(expf(-fabsf(x)));
}

// wave-local ordering fence: per-wave DS ops complete in order on CDNA, so
// for a wave working on its OWN LDS patch this replaces __syncthreads.
// (validated rounds 5-6)
__device__ __forceinline__ void wave_fence() {
    __builtin_amdgcn_wave_barrier();
}

// ---------------------------------------------------------------------------
// Kernel 1: block = one b (512 blocks, 512 threads = 8 waves). Wave w owns
// matrix k=w in its private LDS patch. Round-5 expm (8x8 lanes, 3x3 reg
// tile, A cols in regs), ORDER-8 Taylor (||A||~0.05 -> truncation << 1e-6)
// + 6 squarings, all barriers wave-local. Builds the full 26x208 Row LUT
// (P rows padded + one-hot rows) and stashes it at the head of BOTH halves
// of out[b] for the two store blocks (round-2-validated stash pattern;
// d_ws deliberately unused).
// ---------------------------------------------------------------------------
__global__ __launch_bounds__(512, 2) void expm_lut_kernel(
    const int*   __restrict__ rate_indices,  // B
    const float* __restrict__ tau_kernel,    // NR
    const float* __restrict__ exch,          // K,S,S
    const float* __restrict__ freq,          // S
    float* __restrict__ out)                 // stash target
{
    __shared__ __align__(16) float M[K][2][PDSQ];   // 36864 B
    __shared__ __align__(16) float Row[LUTF];       // 21632 B
    __shared__ float diag_sh[K][S];
    __shared__ float mue_sh[K];

    const int b    = blockIdx.x;
    const int t    = threadIdx.x;
    const int w    = t >> 6;          // wave id == matrix k
    const int lane = t & 63;
    const int li = lane >> 3, lj = lane & 7;
    const int r0 = 3*li, c0 = 3*lj;   // 3x3 tile origin in 24x24

    // ---- LUT static cells (disjoint from P tile cells, no barrier needed):
    //      one-hot rows (row>=20) and zero-pad cols (row<20, s>=20)
    for (int e = t; e < LUTF; e += 512) {
        int row = e / ROWF, c = e - row*ROWF;
        int k = c / EXT, s = c - k*EXT;
        (void)k;
        if (row < S) {
            if (s >= S) Row[e] = 0.f;
        } else {
            Row[e] = (s == row) ? 1.f : 0.f;
        }
    }

    // ---- build A = (Q_w / mue) * tau / 2^6 in M0 (wave-private) ----
    float* M0 = &M[w][0][0];
    float* M1 = &M[w][1][0];
    for (int e = lane; e < PDSQ; e += 64) M0[e] = 0.f;  // pads must be 0
    float tau = softplusf(tau_kernel[rate_indices[b]]);  // uniform, per-lane
    wave_fence();

    const float* E = exch + w * SS;
    for (int e = lane; e < SS; e += 64) {
        int r = e / S, c = e - r*S;
        float v = 0.f;
        if (r != c)
            v = softplusf(0.5f * (E[r*S + c] + E[c*S + r])) * freq[c];
        M0[r*PD + c] = v;
    }
    wave_fence();
    if (lane < S) {
        float d = 0.f;
        #pragma unroll
        for (int j = 0; j < S; ++j) d += M0[lane*PD + j];
        diag_sh[w][lane] = d;
    }
    wave_fence();
    if (lane == 0) {
        float m = 0.f;
        #pragma unroll
        for (int s = 0; s < S; ++s) m += freq[s] * diag_sh[w][s];
        mue_sh[w] = fmaxf(m, 1e-16f);
    }
    wave_fence();
    {
        float scale = tau * 0.015625f;
        float mue   = mue_sh[w];
        for (int e = lane; e < SS; e += 64) {
            int r = e / S, c = e - r*S;
            float v = (r == c) ? -diag_sh[w][r] : M0[r*PD + c];
            M0[r*PD + c] = (v / mue) * scale;
        }
    }
    wave_fence();

    // ---- expm: A cols in regs, P=I+A, order-8 Taylor, 6 squarings ----
    float Ac[S][3];
    #pragma unroll
    for (int j = 0; j < S; ++j) {
        #pragma unroll
        for (int d = 0; d < 3; ++d)
            Ac[j][d] = M0[j*PD + c0 + d];
    }

    float P[3][3];
    #pragma unroll
    for (int dr = 0; dr < 3; ++dr)
        #pragma unroll
        for (int dc = 0; dc < 3; ++dc) {
            int r = r0 + dr, c = c0 + dc;
            P[dr][dc] = M0[r*PD + c] + ((r == c && r < S) ? 1.f : 0.f);
        }

    const float* Tc = M0;
    float* Tn = M1;
    #pragma unroll 1
    for (int i = 2; i <= 8; ++i) {
        float C[3][3] = {{0.f,0.f,0.f},{0.f,0.f,0.f},{0.f,0.f,0.f}};
        #pragma unroll
        for (int jc = 0; jc < 5; ++jc) {
            float4 a0 = *(const float4*)&Tc[(r0+0)*PD + 4*jc];
            float4 a1 = *(const float4*)&Tc[(r0+1)*PD + 4*jc];
            float4 a2 = *(const float4*)&Tc[(r0+2)*PD + 4*jc];
            float t0[4] = {a0.x, a0.y, a0.z, a0.w};
            float t1[4] = {a1.x, a1.y, a1.z, a1.w};
            float t2[4] = {a2.x, a2.y, a2.z, a2.w};
            #pragma unroll
            for (int dj = 0; dj < 4; ++dj) {
                int j = 4*jc + dj;
                #pragma unroll
                for (int dc = 0; dc < 3; ++dc) {
                    C[0][dc] = fmaf(t0[dj], Ac[j][dc], C[0][dc]);
                    C[1][dc] = fmaf(t1[dj], Ac[j][dc], C[1][dc]);
                    C[2][dc] = fmaf(t2[dj], Ac[j][dc], C[2][dc]);
                }
            }
        }
        float inv = 1.0f / (float)i;
        #pragma unroll
        for (int dr = 0; dr < 3; ++dr)
            #pragma unroll
            for (int dc = 0; dc < 3; ++dc) {
                C[dr][dc] *= inv;
                P[dr][dc] += C[dr][dc];
                Tn[(r0+dr)*PD + c0 + dc] = C[dr][dc];
            }
        wave_fence();
        float* tmp = (float*)Tc; Tc = Tn; Tn = tmp;
    }

    // squarings: stage P in the buffer Tn (not holding T), read rows + cols
    #pragma unroll 1
    for (int sq = 0; sq < 6; ++sq) {
        #pragma unroll
        for (int dr = 0; dr < 3; ++dr)
            #pragma unroll
            for (int dc = 0; dc < 3; ++dc)
                Tn[(r0+dr)*PD + c0 + dc] = P[dr][dc];
        wave_fence();
        const float* Pb = Tn;
        float C[3][3] = {{0.f,0.f,0.f},{0.f,0.f,0.f},{0.f,0.f,0.f}};
        #pragma unroll
        for (int jc = 0; jc < 5; ++jc) {
            float4 a0 = *(const float4*)&Pb[(r0+0)*PD + 4*jc];
            float4 a1 = *(const float4*)&Pb[(r0+1)*PD + 4*jc];
            float4 a2 = *(const float4*)&Pb[(r0+2)*PD + 4*jc];
            float t0[4] = {a0.x, a0.y, a0.z, a0.w};
            float t1[4] = {a1.x, a1.y, a1.z, a1.w};
            float t2[4] = {a2.x, a2.y, a2.z, a2.w};
            float cb[4][3];
            #pragma unroll
            for (int dj = 0; dj < 4; ++dj)
                #pragma unroll
                for (int dc = 0; dc < 3; ++dc)
                    cb[dj][dc] = Pb[(4*jc + dj)*PD + c0 + dc];
            #pragma unroll
            for (int dj = 0; dj < 4; ++dj)
                #pragma unroll
                for (int dc = 0; dc < 3; ++dc) {
                    C[0][dc] = fmaf(t0[dj], cb[dj][dc], C[0][dc]);
                    C[1][dc] = fmaf(t1[dj], cb[dj][dc], C[1][dc]);
                    C[2][dc] = fmaf(t2[dj], cb[dj][dc], C[2][dc]);
                }
        }
        #pragma unroll
        for (int dr = 0; dr < 3; ++dr)
            #pragma unroll
            for (int dc = 0; dc < 3; ++dc)
                P[dr][dc] = C[dr][dc];
        wave_fence();
    }

    // ---- P tiles -> Row LUT (r<20, c<20 cells; disjoint from static init) ----
    #pragma unroll
    for (int dr = 0; dr < 3; ++dr) {
        int r = r0 + dr; if (r >= S) continue;
        #pragma unroll
        for (int dc = 0; dc < 3; ++dc) {
            int c = c0 + dc; if (c >= S) continue;
            Row[r*ROWF + w*EXT + c] = P[dr][dc];
        }
    }
    __syncthreads();

    // ---- stash LUT at the head of both halves of out[b] ----
    const float4* Row4 = (const float4*)Row;
    float4* out4 = (float4*)out + (size_t)b * B4;
    for (int u = t; u < LUT4; u += 512) {
        float4 v = Row4[u];
        out4[u] = v;
        out4[H4 + u] = v;
    }
}

// ---------------------------------------------------------------------------
// Kernel 2: block = (b, half). 1024 blocks x 512 threads. Loads the stashed
// LUT -> LDS, then streams out[b][l][:] = Row[inp[l]][:] branch-free:
// u = t + 512*j + 6656*i (j<13, i<4; 6656 = 128*52) -> division-free
// period-13 sweep, 13 independent ds_read->store chains per outer iter,
// stores fully contiguous per block. Low VGPR, high occupancy.
// ---------------------------------------------------------------------------
__global__ __launch_bounds__(512) void store_kernel(
    const int* __restrict__ inputs,  // B,L
    float* __restrict__ out)
{
    __shared__ __align__(16) float4 Row4[LUT4];   // 21632 B
    __shared__ int inp_sh[L/2];                   // 2048 B

    int blk = blockIdx.x;
    int b = blk >> 1, h = blk & 1;
    int t = threadIdx.x;

    float4* base4 = (float4*)out + (size_t)b * B4 + (size_t)h * H4;

    // stash -> LDS; this half's inputs -> LDS
    for (int u = t; u < LUT4; u += 512) Row4[u] = base4[u];
    inp_sh[t] = inputs[b * L + h * (L/2) + t];
    __syncthreads();

    int l0[13], qq[13];
    {
        int uu = t;
        #pragma unroll
        for (int j = 0; j < 13; ++j) {
            l0[j] = uu / 52;
            qq[j] = uu - l0[j] * 52;
            uu += 512;
        }
    }

    #pragma unroll 1
    for (int i = 0; i < 4; ++i) {
        int lbase = i << 7;            // 128*i
        int ubase = t + i * 6656;
        #pragma unroll
        for (int j = 0; j < 13; ++j) {
            int inp = inp_sh[l0[j] + lbase];
            base4[ubase + (j << 9)] = Row4[inp * 52 + qq[j]];
        }
    }
}

// ---------------------------------------------------------------------------
extern "C" void kernel_launch(void* const* d_in, const int* in_sizes, int n_in,
                              void* d_out, int out_size, void* d_ws, size_t ws_size,
                              hipStream_t stream) {
    const int*   inputs  = (const int*)  d_in[0];  // (B,L) int32
    const int*   rate_ix = (const int*)  d_in[1];  // (B,) int32
    const float* tau_k   = (const float*)d_in[2];  // (NR,) f32
    const float* exch    = (const float*)d_in[3];  // (K,S,S) f32
    const float* freq    = (const float*)d_in[4];  // (S,) f32
    float* out = (float*)d_out;

    (void)d_ws; (void)ws_size;  // intentionally unused

    expm_lut_kernel<<<B, 512, 0, stream>>>(rate_ix, tau_k, exch, freq, out);
    store_kernel<<<B * 2, 512, 0, stream>>>(inputs, out);
}